// Round 1
// baseline (5484.010 us; speedup 1.0000x reference)
//
#include <hip/hip_runtime.h>
#include <hip/hip_bf16.h>
#include <stdint.h>

#define NB 8
#define NC 256
#define NHW 4096
#define NG 32
#define CPG 8
#define GELEMS (CPG*NHW)
#define OQKV 768
#define EPS 1e-5f
#define RB 16
#define MBLK 64

typedef unsigned short u16;
typedef unsigned int u32;

__device__ __forceinline__ float bf2f(u16 u){ return __uint_as_float((u32)u << 16); }
__device__ __forceinline__ u16 f2bf(float f){
  u32 i = __float_as_uint(f);
  u32 r = i + 0x7fffu + ((i >> 16) & 1u);   // round-to-nearest-even
  return (u16)(r >> 16);
}

// ---------------- GroupNorm statistics: one block per (b,g) ----------------
__global__ __launch_bounds__(256) void gn_stats_k(const float* __restrict__ x,
                                                  float* __restrict__ stats){
  int bg = blockIdx.x;                       // b*NG + g
  const float* xp = x + (size_t)bg * GELEMS;
  float s = 0.f, s2 = 0.f;
  for (int i = threadIdx.x * 4; i < GELEMS; i += 256 * 4) {
    float4 v = *(const float4*)(xp + i);
    s  += v.x + v.y + v.z + v.w;
    s2 += v.x*v.x + v.y*v.y + v.z*v.z + v.w*v.w;
  }
  #pragma unroll
  for (int off = 32; off; off >>= 1) { s += __shfl_xor(s, off); s2 += __shfl_xor(s2, off); }
  __shared__ float rs[4], rs2[4];
  int w = threadIdx.x >> 6;
  if ((threadIdx.x & 63) == 0) { rs[w] = s; rs2[w] = s2; }
  __syncthreads();
  if (threadIdx.x == 0) {
    float ts = rs[0]+rs[1]+rs[2]+rs[3], t2 = rs2[0]+rs2[1]+rs2[2]+rs2[3];
    float mean = ts * (1.f/GELEMS);
    float var  = t2 * (1.f/GELEMS) - mean*mean;
    stats[2*bg]   = mean;
    stats[2*bg+1] = rsqrtf(var + EPS);
  }
}

// ---------------- fold GN into per-(b,c) scale/shift ----------------
__global__ __launch_bounds__(256) void gn_coef_k(const float* __restrict__ stats,
                                                 const float* __restrict__ gamma,
                                                 const float* __restrict__ beta,
                                                 float* __restrict__ coef){
  int i = blockIdx.x * 256 + threadIdx.x;    // b*NC + c
  if (i >= NB*NC) return;
  int b = i >> 8, c = i & 255;
  float mean = stats[2*(b*NG + (c>>3))];
  float rstd = stats[2*(b*NG + (c>>3)) + 1];
  float sc = gamma[c] * rstd;
  coef[2*i]   = sc;
  coef[2*i+1] = beta[c] - mean * sc;
}

// ---------------- fused GN + QKV 1x1 conv, bf16 output ----------------
// block: 256 threads = 256 consecutive n; each thread computes 16 o outputs.
__global__ __launch_bounds__(256) void qkv_k(const float* __restrict__ x,
                                             const float* __restrict__ coef,
                                             const float* __restrict__ w_qkv,
                                             const float* __restrict__ b_qkv,
                                             u16* __restrict__ qkv){
  int idx = blockIdx.x;
  int og = idx % 48;                 // 48 groups of 16 outputs
  int t  = idx / 48;
  int nc = t & 15;
  int b  = t >> 4;
  int n  = nc * 256 + threadIdx.x;
  const float* xb = x + (size_t)b * NC * NHW + n;
  const float* cf = coef + b * NC * 2;
  int ob = og * 16;
  float acc[16];
  #pragma unroll
  for (int j = 0; j < 16; ++j) acc[j] = b_qkv[ob + j];
  for (int c = 0; c < NC; ++c) {
    float h = xb[(size_t)c * NHW] * cf[2*c] + cf[2*c+1];
    const float* wr = w_qkv + (size_t)ob * NC + c;
    #pragma unroll
    for (int j = 0; j < 16; ++j) acc[j] += h * wr[(size_t)j * NC];
  }
  u16* qp = qkv + ((size_t)b * OQKV + ob) * NHW + n;
  #pragma unroll
  for (int j = 0; j < 16; ++j) qp[(size_t)j * NHW] = f2bf(acc[j]);
}

// ---------------- flash attention + fused proj + residual ----------------
// block: 4 waves, each wave owns 4 rows (RB=16 rows/block). online softmax.
__global__ __launch_bounds__(256) void attn_k(const float* __restrict__ x,
                                              const u16* __restrict__ qkv,
                                              const float* __restrict__ w_proj,
                                              const float* __restrict__ b_proj,
                                              float* __restrict__ out){
  __shared__ u16   VT[64][264];        // V tile transposed [m][c], row pad->528B
  __shared__ float qsf[4][4][256];     // per-wave Q rows (fp32); reused as attn-out
  __shared__ float ps[4][4][64];       // per-wave softmax p values

  int blk = blockIdx.x;
  int b  = blk >> 8;                   // 256 row-blocks per batch
  int n0 = (blk & 255) * RB;
  int wid  = threadIdx.x >> 6;
  int lane = threadIdx.x & 63;

  const u16* Qb = qkv + (size_t)b * OQKV * NHW;
  const u16* Kb = Qb + (size_t)NC * NHW;
  const u16* Vb = Kb + (size_t)NC * NHW;

  // prologue: load Q rows into LDS as fp32 (thread t loads channel c=t)
  {
    int c = threadIdx.x;
    const u16* qp = Qb + (size_t)c * NHW + n0;
    #pragma unroll
    for (int i = 0; i < RB; ++i) qsf[i >> 2][i & 3][c] = bf2f(qp[i]);
  }

  float acc[4][4];
  #pragma unroll
  for (int r = 0; r < 4; ++r)
    #pragma unroll
    for (int j = 0; j < 4; ++j) acc[r][j] = 0.f;
  float mrun[4], lrun[4];
  #pragma unroll
  for (int r = 0; r < 4; ++r) { mrun[r] = -1e30f; lrun[r] = 0.f; }

  for (int mb0 = 0; mb0 < NHW; mb0 += MBLK) {
    __syncthreads();   // prev PV done (and Q prologue visible on first iter)
    // stage V tile transposed: wave w loads channels [w*64, w*64+64)
    {
      const u16* vp = Vb + (size_t)(wid * 64) * NHW + mb0 + lane;
      #pragma unroll 8
      for (int k = 0; k < 64; ++k) VT[lane][wid * 64 + k] = vp[(size_t)k * NHW];
    }
    __syncthreads();

    // QK^T : lane owns column m = mb0+lane; K read from global (L2 resident)
    float s[4] = {0.f, 0.f, 0.f, 0.f};
    const u16* kp = Kb + mb0 + lane;
    for (int c4 = 0; c4 < 64; ++c4) {
      float kv0 = bf2f(kp[(size_t)(c4*4+0) * NHW]);
      float kv1 = bf2f(kp[(size_t)(c4*4+1) * NHW]);
      float kv2 = bf2f(kp[(size_t)(c4*4+2) * NHW]);
      float kv3 = bf2f(kp[(size_t)(c4*4+3) * NHW]);
      #pragma unroll
      for (int r = 0; r < 4; ++r) {
        float4 q = *(const float4*)&qsf[wid][r][c4*4];
        s[r] += q.x*kv0 + q.y*kv1 + q.z*kv2 + q.w*kv3;
      }
    }
    // online softmax per row
    #pragma unroll
    for (int r = 0; r < 4; ++r) {
      float sv = s[r] * 0.0625f;
      float cmax = sv;
      #pragma unroll
      for (int off = 32; off; off >>= 1) cmax = fmaxf(cmax, __shfl_xor(cmax, off));
      float mnew = fmaxf(mrun[r], cmax);
      float p    = __expf(sv - mnew);
      float corr = __expf(mrun[r] - mnew);
      mrun[r] = mnew;
      float psum = p;
      #pragma unroll
      for (int off = 32; off; off >>= 1) psum += __shfl_xor(psum, off);
      lrun[r] = lrun[r] * corr + psum;
      #pragma unroll
      for (int j = 0; j < 4; ++j) acc[r][j] *= corr;
      ps[wid][r][lane] = p;
    }
    // PV: lane owns channels 4*lane..4*lane+3
    for (int mq = 0; mq < 64; mq += 4) {
      float prr[4][4];
      #pragma unroll
      for (int r = 0; r < 4; ++r) *(float4*)prr[r] = *(const float4*)&ps[wid][r][mq];
      #pragma unroll
      for (int k = 0; k < 4; ++k) {
        uint2 vv = *(const uint2*)&VT[mq + k][4 * lane];
        float v0 = __uint_as_float(vv.x << 16);
        float v1 = __uint_as_float(vv.x & 0xffff0000u);
        float v2 = __uint_as_float(vv.y << 16);
        float v3 = __uint_as_float(vv.y & 0xffff0000u);
        #pragma unroll
        for (int r = 0; r < 4; ++r) {
          acc[r][0] += prr[r][k] * v0;
          acc[r][1] += prr[r][k] * v1;
          acc[r][2] += prr[r][k] * v2;
          acc[r][3] += prr[r][k] * v3;
        }
      }
    }
  }

  // write attn-out rows into qsf (alias; each wave touches only its own region)
  #pragma unroll
  for (int r = 0; r < 4; ++r) {
    float inv = 1.f / lrun[r];
    float4 o4 = { acc[r][0]*inv, acc[r][1]*inv, acc[r][2]*inv, acc[r][3]*inv };
    *(float4*)&qsf[wid][r][4 * lane] = o4;
  }

  // fused proj + residual. lane handles o = lane + 64j; w row reused across 4 rows.
  #pragma unroll
  for (int j = 0; j < 4; ++j) {
    int o = lane + 64 * j;
    const float* wr = w_proj + (size_t)o * NC;
    float bp = b_proj[o];
    float pa[4] = { bp, bp, bp, bp };
    for (int c4 = 0; c4 < 64; ++c4) {
      float4 wv = *(const float4*)(wr + c4 * 4);
      #pragma unroll
      for (int r = 0; r < 4; ++r) {
        float4 a4 = *(const float4*)&qsf[wid][r][c4 * 4];
        pa[r] += wv.x*a4.x + wv.y*a4.y + wv.z*a4.z + wv.w*a4.w;
      }
    }
    #pragma unroll
    for (int r = 0; r < 4; ++r) {
      size_t oi = ((size_t)b * NC + o) * NHW + n0 + wid * 4 + r;
      out[oi] = x[oi] + pa[r];
    }
  }
}

extern "C" void kernel_launch(void* const* d_in, const int* in_sizes, int n_in,
                              void* d_out, int out_size, void* d_ws, size_t ws_size,
                              hipStream_t stream) {
  const float* x      = (const float*)d_in[0];
  const float* gamma  = (const float*)d_in[1];
  const float* beta   = (const float*)d_in[2];
  const float* w_qkv  = (const float*)d_in[3];
  const float* b_qkv  = (const float*)d_in[4];
  const float* w_proj = (const float*)d_in[5];
  const float* b_proj = (const float*)d_in[6];
  float* out = (float*)d_out;

  float* stats = (float*)d_ws;                       // 2*NB*NG floats
  float* coef  = stats + 2 * NB * NG;                // 2*NB*NC floats
  u16*   qkv   = (u16*)((char*)d_ws + 18432);        // NB*OQKV*NHW bf16 (~50.3MB)

  gn_stats_k<<<NB * NG, 256, 0, stream>>>(x, stats);
  gn_coef_k<<<(NB * NC + 255) / 256, 256, 0, stream>>>(stats, gamma, beta, coef);
  qkv_k<<<NB * 16 * 48, 256, 0, stream>>>(x, coef, w_qkv, b_qkv, qkv);
  attn_k<<<NB * 256, 256, 0, stream>>>(x, qkv, w_proj, b_proj, out);
}

// Round 2
// 523.512 us; speedup vs baseline: 10.4754x; 10.4754x over previous
//
#include <hip/hip_runtime.h>
#include <stdint.h>

#define NB 8
#define NC 256
#define NHW 4096
#define NG 32
#define GELEMS (8*NHW)
#define EPS 1e-5f

typedef unsigned short u16;
typedef unsigned int u32;
typedef __attribute__((ext_vector_type(8))) short bf16x8;
typedef __attribute__((ext_vector_type(4))) float f32x4;

__device__ __forceinline__ float bf2f(u16 u){ return __uint_as_float((u32)u << 16); }
__device__ __forceinline__ u16 f2bf(float f){
  u32 i = __float_as_uint(f);
  u32 r = i + 0x7fffu + ((i >> 16) & 1u);   // RNE
  return (u16)(r >> 16);
}
__device__ __forceinline__ u32 pack2(float a, float b){
  return (u32)f2bf(a) | ((u32)f2bf(b) << 16);
}

#define GLD16(g, l) __builtin_amdgcn_global_load_lds( \
    (const __attribute__((address_space(1))) u32*)(g), \
    (__attribute__((address_space(3))) u32*)(l), 16, 0, 0)

// ---------------- GroupNorm statistics: one block per (b,g) ----------------
__global__ __launch_bounds__(256) void gn_stats_k(const float* __restrict__ x,
                                                  float* __restrict__ stats){
  int bg = blockIdx.x;
  const float* xp = x + (size_t)bg * GELEMS;
  float s = 0.f, s2 = 0.f;
  for (int i = threadIdx.x * 4; i < GELEMS; i += 256 * 4) {
    float4 v = *(const float4*)(xp + i);
    s  += v.x + v.y + v.z + v.w;
    s2 += v.x*v.x + v.y*v.y + v.z*v.z + v.w*v.w;
  }
  #pragma unroll
  for (int off = 32; off; off >>= 1) { s += __shfl_xor(s, off); s2 += __shfl_xor(s2, off); }
  __shared__ float rs[4], rs2[4];
  int w = threadIdx.x >> 6;
  if ((threadIdx.x & 63) == 0) { rs[w] = s; rs2[w] = s2; }
  __syncthreads();
  if (threadIdx.x == 0) {
    float ts = rs[0]+rs[1]+rs[2]+rs[3], t2 = rs2[0]+rs2[1]+rs2[2]+rs2[3];
    float mean = ts * (1.f/GELEMS);
    float var  = t2 * (1.f/GELEMS) - mean*mean;
    stats[2*bg]   = mean;
    stats[2*bg+1] = rsqrtf(var + EPS);
  }
}

__global__ __launch_bounds__(256) void gn_coef_k(const float* __restrict__ stats,
                                                 const float* __restrict__ gamma,
                                                 const float* __restrict__ beta,
                                                 float* __restrict__ coef){
  int i = blockIdx.x * 256 + threadIdx.x;
  if (i >= NB*NC) return;
  int b = i >> 8, c = i & 255;
  float mean = stats[2*(b*NG + (c>>3))];
  float rstd = stats[2*(b*NG + (c>>3)) + 1];
  float sc = gamma[c] * rstd;
  coef[2*i]   = sc;
  coef[2*i+1] = beta[c] - mean * sc;
}

// -------- fused GN + QKV 1x1 conv; Q,K -> [n][c] bf16 (Q pre-scaled), V -> [c][n] --------
__global__ __launch_bounds__(256) void qkv_k(const float* __restrict__ x,
                                             const float* __restrict__ coef,
                                             const float* __restrict__ w_qkv,
                                             const float* __restrict__ b_qkv,
                                             u16* __restrict__ qT, u16* __restrict__ kT,
                                             u16* __restrict__ vS){
  int idx0 = blockIdx.x;
  int idx = (idx0 >> 3) + (idx0 & 7) * 768;   // XCD swizzle: batch b -> XCD b
  int og = idx % 48;
  int t  = idx / 48;
  int nc = t & 15;
  int b  = t >> 4;
  int n  = nc * 256 + threadIdx.x;
  const float* xb = x + (size_t)b * NC * NHW + n;
  const float* cf = coef + b * NC * 2;
  int ob = og * 16;
  float acc[16];
  #pragma unroll
  for (int j = 0; j < 16; ++j) acc[j] = b_qkv[ob + j];
  for (int c = 0; c < NC; ++c) {
    float h = xb[(size_t)c * NHW] * cf[2*c] + cf[2*c+1];
    const float* wr = w_qkv + (size_t)ob * NC + c;
    #pragma unroll
    for (int j = 0; j < 16; ++j) acc[j] += h * wr[(size_t)j * NC];
  }
  if (ob < 512) {
    float sc = (ob < 256) ? 0.0625f : 1.0f;   // fold 1/sqrt(C) into Q (exact in bf16)
    union { u16 h[16]; uint4 q[2]; } u;
    #pragma unroll
    for (int j = 0; j < 16; ++j) u.h[j] = f2bf(acc[j] * sc);
    u16* p = (ob < 256) ? (qT + ((size_t)(b*NHW + n))*NC + ob)
                        : (kT + ((size_t)(b*NHW + n))*NC + (ob - 256));
    *(uint4*)p = u.q[0];
    *(uint4*)(p + 8) = u.q[1];
  } else {
    u16* p = vS + ((size_t)(b*NC) + (ob - 512)) * NHW + n;
    #pragma unroll
    for (int j = 0; j < 16; ++j) p[(size_t)j * NHW] = f2bf(acc[j]);
  }
}

__global__ __launch_bounds__(256) void cvtw_k(const float* __restrict__ w,
                                              u16* __restrict__ wbf){
  int i = blockIdx.x * 256 + threadIdx.x;
  wbf[i] = f2bf(w[i]);
}

// ---------------- MFMA flash attention + fused proj + residual ----------------
// 4 waves x 16 q-rows; KV block 64; swapped QK^T; swizzled LDS tiles.
template<int WBF>
__global__ __launch_bounds__(256, 2) void attn_k(const float* __restrict__ x,
    const u16* __restrict__ qT, const u16* __restrict__ kT, const u16* __restrict__ vS,
    const float* __restrict__ w_proj, const u16* __restrict__ wbf,
    const float* __restrict__ b_proj, float* __restrict__ out){
  __shared__ char smem[73728];
  u16* Klds = (u16*)smem;               // [64][256] bf16, chunk^=(row&7) swizzle
  u16* Vlds = (u16*)(smem + 32768);     // [256][64] bf16, swizzled
  float* Olds = (float*)smem;           // epilogue alias: [4][16][256] f32

  int bid = blockIdx.x;
  int wg = ((bid & 7) << 6) | (bid >> 3);   // XCD swizzle (512 = 8*64, bijective)
  int b  = wg >> 6;
  int n0 = (wg & 63) << 6;
  int w = threadIdx.x >> 6, lane = threadIdx.x & 63;
  int lo = lane & 15, g = lane >> 4;
  int sw = lo & 7;

  const u16* qTb = qT + (size_t)b * NHW * NC;
  const u16* kTb = kT + (size_t)b * NHW * NC;
  const u16* vSb = vS + (size_t)b * NC * NHW;

  // Q fragments (stationary): rows n0+w*16+lo, k = kc*32 + g*8 + e
  bf16x8 qf[8];
  {
    const u16* qp = qTb + (size_t)(n0 + w*16 + lo) * NC + g*8;
    #pragma unroll
    for (int kc = 0; kc < 8; ++kc) qf[kc] = *(const bf16x8*)(qp + kc*32);
  }

  // staging address precompute (loop-invariant): linear LDS dest + inverse-swizzled src
  int koff[8], voff[8];
  #pragma unroll
  for (int i = 0; i < 8; ++i) {
    int o = w*8192 + i*1024 + lane*16;       // byte offset within 32KB region
    int mr = o >> 9;                          // K tile row (m-local), 512B rows
    int kch = ((o >> 4) & 31) ^ (mr & 7);
    koff[i] = mr*NC + kch*8;                  // u16 elements (+ m0*NC per step)
    int cr = o >> 7;                          // V tile row (c), 128B rows
    int vch = ((o >> 4) & 7) ^ (cr & 7);
    voff[i] = cr*NHW + vch*8;                 // u16 elements (+ m0 per step)
  }

  f32x4 oacc[16];
  #pragma unroll
  for (int i = 0; i < 16; ++i) oacc[i] = (f32x4){0.f,0.f,0.f,0.f};
  float mrun = -1e30f, lrun = 0.f;

  char* Pw = smem + 65536 + w*2048;           // per-wave P buffer [16][64] bf16, swizzled

  for (int m0 = 0; m0 < NHW; m0 += 64) {
    __syncthreads();
    const u16* kp = kTb + (size_t)m0 * NC;
    const u16* vp = vSb + m0;
    #pragma unroll
    for (int i = 0; i < 8; ++i) {
      GLD16(kp + koff[i], smem + w*8192 + i*1024);
      GLD16(vp + voff[i], smem + 32768 + w*8192 + i*1024);
    }
    __syncthreads();

    // swapped QK^T: st[mt] = S^T (rows m = mt*16+4g+r, col n = lo)
    f32x4 st[4];
    #pragma unroll
    for (int mt = 0; mt < 4; ++mt) st[mt] = (f32x4){0.f,0.f,0.f,0.f};
    #pragma unroll
    for (int kc = 0; kc < 8; ++kc) {
      #pragma unroll
      for (int mt = 0; mt < 4; ++mt) {
        int ch = (kc*4 + g) ^ sw;
        bf16x8 kf = *(const bf16x8*)(Klds + (mt*16 + lo)*NC + ch*8);
        st[mt] = __builtin_amdgcn_mfma_f32_16x16x32_bf16(kf, qf[kc], st[mt], 0, 0, 0);
      }
    }

    // online softmax (row n = lo is lane-local: 16 in-lane values + 2 shuffles)
    float pmax = -1e30f;
    #pragma unroll
    for (int mt = 0; mt < 4; ++mt)
      #pragma unroll
      for (int r = 0; r < 4; ++r) pmax = fmaxf(pmax, st[mt][r]);
    pmax = fmaxf(pmax, __shfl_xor(pmax, 16));
    pmax = fmaxf(pmax, __shfl_xor(pmax, 32));

    if (!__all(pmax - mrun <= 8.f)) {         // defer-max (T13): rare rescale
      float mnew = fmaxf(mrun, pmax);
      float corr = __expf(mrun - mnew);
      mrun = mnew;
      lrun *= corr;
      float c0 = __shfl(corr, 4*g+0), c1 = __shfl(corr, 4*g+1);
      float c2 = __shfl(corr, 4*g+2), c3 = __shfl(corr, 4*g+3);
      #pragma unroll
      for (int ct = 0; ct < 16; ++ct) {
        oacc[ct][0] *= c0; oacc[ct][1] *= c1; oacc[ct][2] *= c2; oacc[ct][3] *= c3;
      }
    }

    float psum = 0.f;
    #pragma unroll
    for (int mt = 0; mt < 4; ++mt) {
      float p0 = __expf(st[mt][0] - mrun);
      float p1 = __expf(st[mt][1] - mrun);
      float p2 = __expf(st[mt][2] - mrun);
      float p3 = __expf(st[mt][3] - mrun);
      psum += (p0 + p1) + (p2 + p3);
      uint2 pk = { pack2(p0, p1), pack2(p2, p3) };
      // row lo, m-bytes 32*mt+8*g(+2r): chunk = 2mt+(g>>1) (^sw), inner 8B = (g&1)*8
      *(uint2*)(Pw + lo*128 + ((((2*mt + (g>>1)) ^ sw)) << 4) + ((g&1) << 3)) = pk;
    }
    psum += __shfl_xor(psum, 16);
    psum += __shfl_xor(psum, 32);
    lrun += psum;

    // PV: A = P (rows n), B = V[m][c] from swizzled Vlds
    #pragma unroll
    for (int ks = 0; ks < 2; ++ks) {
      bf16x8 pa = *(const bf16x8*)(Pw + lo*128 + (((ks*4 + g) ^ sw) << 4));
      #pragma unroll
      for (int ct = 0; ct < 16; ++ct) {
        int ch = (ks*4 + g) ^ sw;
        bf16x8 vf = *(const bf16x8*)(Vlds + (ct*16 + lo)*64 + ch*8);
        oacc[ct] = __builtin_amdgcn_mfma_f32_16x16x32_bf16(pa, vf, oacc[ct], 0, 0, 0);
      }
    }
  }

  // ---------------- epilogue: O/l -> LDS, proj MFMA, bias + residual ----------------
  __syncthreads();                           // all K/V reads done before aliasing
  float linv = 1.f / lrun;
  float l0 = __shfl(linv, 4*g+0), l1 = __shfl(linv, 4*g+1);
  float l2 = __shfl(linv, 4*g+2), l3 = __shfl(linv, 4*g+3);
  float* Ow = Olds + w*4096;                 // [16][256] f32, per-wave
  #pragma unroll
  for (int ct = 0; ct < 16; ++ct) {
    int col = ct*16 + lo;
    Ow[(4*g+0)*256 + col] = oacc[ct][0] * l0;
    Ow[(4*g+1)*256 + col] = oacc[ct][1] * l1;
    Ow[(4*g+2)*256 + col] = oacc[ct][2] * l2;
    Ow[(4*g+3)*256 + col] = oacc[ct][3] * l3;
  }

  f32x4 pacc[16];
  #pragma unroll
  for (int i = 0; i < 16; ++i) pacc[i] = (f32x4){0.f,0.f,0.f,0.f};
  #pragma unroll
  for (int ks = 0; ks < 8; ++ks) {
    const float* ap = Ow + lo*256 + ks*32 + g*8;
    float4 a0 = *(const float4*)ap;
    float4 a1 = *(const float4*)(ap + 4);
    union { u16 h[8]; bf16x8 v; } au;
    au.h[0]=f2bf(a0.x); au.h[1]=f2bf(a0.y); au.h[2]=f2bf(a0.z); au.h[3]=f2bf(a0.w);
    au.h[4]=f2bf(a1.x); au.h[5]=f2bf(a1.y); au.h[6]=f2bf(a1.z); au.h[7]=f2bf(a1.w);
    bf16x8 af = au.v;
    #pragma unroll
    for (int ot = 0; ot < 16; ++ot) {
      bf16x8 bf;
      if (WBF) {
        bf = *(const bf16x8*)(wbf + (size_t)(ot*16 + lo)*NC + ks*32 + g*8);
      } else {
        const float* wp = w_proj + (size_t)(ot*16 + lo)*NC + ks*32 + g*8;
        float4 b0 = *(const float4*)wp;
        float4 b1 = *(const float4*)(wp + 4);
        union { u16 h[8]; bf16x8 v; } bu;
        bu.h[0]=f2bf(b0.x); bu.h[1]=f2bf(b0.y); bu.h[2]=f2bf(b0.z); bu.h[3]=f2bf(b0.w);
        bu.h[4]=f2bf(b1.x); bu.h[5]=f2bf(b1.y); bu.h[6]=f2bf(b1.z); bu.h[7]=f2bf(b1.w);
        bf = bu.v;
      }
      pacc[ot] = __builtin_amdgcn_mfma_f32_16x16x32_bf16(af, bf, pacc[ot], 0, 0, 0);
    }
  }

  int nrow = n0 + w*16 + 4*g;
  #pragma unroll
  for (int ot = 0; ot < 16; ++ot) {
    int o = ot*16 + lo;
    float bp = b_proj[o];
    size_t base = ((size_t)(b*NC + o)) * NHW + nrow;
    float4 xr = *(const float4*)(x + base);
    float4 ov = { pacc[ot][0] + bp + xr.x, pacc[ot][1] + bp + xr.y,
                  pacc[ot][2] + bp + xr.z, pacc[ot][3] + bp + xr.w };
    *(float4*)(out + base) = ov;
  }
}

extern "C" void kernel_launch(void* const* d_in, const int* in_sizes, int n_in,
                              void* d_out, int out_size, void* d_ws, size_t ws_size,
                              hipStream_t stream) {
  const float* x      = (const float*)d_in[0];
  const float* gamma  = (const float*)d_in[1];
  const float* beta   = (const float*)d_in[2];
  const float* w_qkv  = (const float*)d_in[3];
  const float* b_qkv  = (const float*)d_in[4];
  const float* w_proj = (const float*)d_in[5];
  const float* b_proj = (const float*)d_in[6];
  float* out = (float*)d_out;

  float* stats = (float*)d_ws;                        // 512 f
  float* coef  = stats + 2 * NB * NG;                 // 4096 f
  u16* qT = (u16*)((char*)d_ws + 18432);              // [b][n][c] 16MB
  u16* kT = qT + (size_t)NB * NHW * NC;               // [b][n][c] 16MB
  u16* vS = kT + (size_t)NB * NHW * NC;               // [b][c][n] 16MB
  u16* wbf = vS + (size_t)NB * NC * NHW;              // 128KB (optional)
  size_t need = 18432 + (size_t)3 * NB * NHW * NC * 2 + (size_t)NC * NC * 2;

  gn_stats_k<<<NB * NG, 256, 0, stream>>>(x, stats);
  gn_coef_k<<<(NB * NC + 255) / 256, 256, 0, stream>>>(stats, gamma, beta, coef);
  qkv_k<<<NB * 16 * 48, 256, 0, stream>>>(x, coef, w_qkv, b_qkv, qT, kT, vS);
  if (ws_size >= need) {
    cvtw_k<<<NC * NC / 256, 256, 0, stream>>>(w_proj, wbf);
    attn_k<1><<<512, 256, 0, stream>>>(x, qT, kT, vS, w_proj, wbf, b_proj, out);
  } else {
    attn_k<0><<<512, 256, 0, stream>>>(x, qT, kT, vS, w_proj, wbf, b_proj, out);
  }
}

// Round 3
// 274.561 us; speedup vs baseline: 19.9737x; 1.9067x over previous
//
#include <hip/hip_runtime.h>
#include <stdint.h>

#define NB 8
#define NC 256
#define NHW 4096
#define NG 32
#define GELEMS (8*NHW)
#define EPS 1e-5f

typedef unsigned short u16;
typedef unsigned int u32;
typedef __attribute__((ext_vector_type(8))) short bf16x8;
typedef __attribute__((ext_vector_type(4))) float f32x4;

__device__ __forceinline__ float bf2f(u16 u){ return __uint_as_float((u32)u << 16); }
__device__ __forceinline__ u16 f2bf(float f){
  u32 i = __float_as_uint(f);
  u32 r = i + 0x7fffu + ((i >> 16) & 1u);   // RNE
  return (u16)(r >> 16);
}
__device__ __forceinline__ u32 pack2(float a, float b){
  return (u32)f2bf(a) | ((u32)f2bf(b) << 16);
}

#define GLD16(g, l) __builtin_amdgcn_global_load_lds( \
    (const __attribute__((address_space(1))) u32*)(g), \
    (__attribute__((address_space(3))) u32*)(l), 16, 0, 0)

// ---------------- GroupNorm statistics: one block per (b,g) ----------------
__global__ __launch_bounds__(256) void gn_stats_k(const float* __restrict__ x,
                                                  float* __restrict__ stats){
  int bg = blockIdx.x;
  const float* xp = x + (size_t)bg * GELEMS;
  float s = 0.f, s2 = 0.f;
  for (int i = threadIdx.x * 4; i < GELEMS; i += 256 * 4) {
    float4 v = *(const float4*)(xp + i);
    s  += v.x + v.y + v.z + v.w;
    s2 += v.x*v.x + v.y*v.y + v.z*v.z + v.w*v.w;
  }
  #pragma unroll
  for (int off = 32; off; off >>= 1) { s += __shfl_xor(s, off); s2 += __shfl_xor(s2, off); }
  __shared__ float rs[4], rs2[4];
  int w = threadIdx.x >> 6;
  if ((threadIdx.x & 63) == 0) { rs[w] = s; rs2[w] = s2; }
  __syncthreads();
  if (threadIdx.x == 0) {
    float ts = rs[0]+rs[1]+rs[2]+rs[3], t2 = rs2[0]+rs2[1]+rs2[2]+rs2[3];
    float mean = ts * (1.f/GELEMS);
    float var  = t2 * (1.f/GELEMS) - mean*mean;
    stats[2*bg]   = mean;
    stats[2*bg+1] = rsqrtf(var + EPS);
  }
}

__global__ __launch_bounds__(256) void gn_coef_k(const float* __restrict__ stats,
                                                 const float* __restrict__ gamma,
                                                 const float* __restrict__ beta,
                                                 float* __restrict__ coef){
  int i = blockIdx.x * 256 + threadIdx.x;
  if (i >= NB*NC) return;
  int b = i >> 8, c = i & 255;
  float mean = stats[2*(b*NG + (c>>3))];
  float rstd = stats[2*(b*NG + (c>>3)) + 1];
  float sc = gamma[c] * rstd;
  coef[2*i]   = sc;
  coef[2*i+1] = beta[c] - mean * sc;
}

__global__ __launch_bounds__(256) void cvtw_k(const float* __restrict__ w,
                                              u16* __restrict__ wbf){
  int i = blockIdx.x * 256 + threadIdx.x;
  wbf[i] = f2bf(w[i]);
}

// -------- MFMA fused GN + QKV: Q,K -> [n][c] bf16 (Q pre-scaled), V -> [c][n] --------
// 512 blocks (2/CU), 4 waves; wave owns 16 pixels; H register-stationary (K=256);
// 48 o-tiles of 16, W staged via global_load_lds into XOR-swizzled LDS, dbuf.
__global__ __launch_bounds__(256, 2) void qkv_mfma_k(const float* __restrict__ x,
    const float* __restrict__ coef, const u16* __restrict__ wqbf,
    const float* __restrict__ b_qkv,
    u16* __restrict__ qT, u16* __restrict__ kT, u16* __restrict__ vS){
  __shared__ u16 Wbuf[2][4096];              // [16][256] bf16, chunk^=(row&7)

  int bid = blockIdx.x;
  int wg = ((bid & 7) << 6) | (bid >> 3);    // XCD swizzle: batch b -> XCD b
  int b  = wg >> 6;
  int n0 = (wg & 63) << 6;
  int w = threadIdx.x >> 6, lane = threadIdx.x & 63;
  int lo = lane & 15, g = lane >> 4;
  int n = n0 + w*16 + lo;

  // staging: linear LDS dest (tid*16 bytes), inverse-swizzled global source
  int row1 = w*2 + (lane >> 5);              // rows 0..7 (round 1), +8 (round 2)
  int sxor = ((lane & 31) ^ (row1 & 7)) * 8;
  int src1 = row1 * 256 + sxor;
  int src2 = (row1 + 8) * 256 + sxor;        // (row+8)&7 == row&7

  auto STAGE = [&](int bufi, int ot) {
    const u16* src = wqbf + ot * 4096;
    GLD16(src + src1, &Wbuf[bufi][w * 512]);
    GLD16(src + src2, &Wbuf[bufi][2048 + w * 512]);
  };

  STAGE(0, 0);

  // H fragments (register-stationary): j = lo, k = kc*32 + g*8 + e
  bf16x8 hf[8];
  {
    const float* xb = x + (size_t)b * NC * NHW + n;
    const float* cf = coef + b * 512;
    #pragma unroll
    for (int kc = 0; kc < 8; ++kc) {
      union { u32 u[4]; bf16x8 v; } hu;
      #pragma unroll
      for (int p = 0; p < 4; ++p) {
        int c = kc*32 + g*8 + p*2;
        float2 s0 = *(const float2*)(cf + 2*c);
        float2 s1 = *(const float2*)(cf + 2*c + 2);
        float f0 = xb[(size_t)c * NHW]     * s0.x + s0.y;
        float f1 = xb[(size_t)(c+1) * NHW] * s1.x + s1.y;
        hu.u[p] = pack2(f0, f1);
      }
      hf[kc] = hu.v;
    }
  }

  u16* qrow = qT + ((size_t)(b * NHW + n)) * NC;
  u16* krow = kT + ((size_t)(b * NHW + n)) * NC;

  for (int ot = 0; ot < 48; ++ot) {
    __syncthreads();                         // staged tile ready; prev reads drained
    if (ot < 47) STAGE((ot + 1) & 1, ot + 1);
    const u16* Wl = Wbuf[ot & 1];
    int sw = lo & 7;
    f32x4 acc = (f32x4){0.f, 0.f, 0.f, 0.f};

    if (ot < 32) {
      // C[o][j]: o = ot*16+4g+r, j = lo
      #pragma unroll
      for (int kc = 0; kc < 8; ++kc) {
        bf16x8 wf = *(const bf16x8*)(Wl + lo*256 + ((kc*4 + g) ^ sw) * 8);
        acc = __builtin_amdgcn_mfma_f32_16x16x32_bf16(wf, hf[kc], acc, 0, 0, 0);
      }
      float4 bq = *(const float4*)(b_qkv + ot*16 + 4*g);
      float v0 = acc[0]+bq.x, v1 = acc[1]+bq.y, v2 = acc[2]+bq.z, v3 = acc[3]+bq.w;
      if (ot < 16) {                         // fold 1/sqrt(C) into Q
        v0 *= 0.0625f; v1 *= 0.0625f; v2 *= 0.0625f; v3 *= 0.0625f;
        uint2 st = { pack2(v0, v1), pack2(v2, v3) };
        *(uint2*)(qrow + ot*16 + 4*g) = st;
      } else {
        uint2 st = { pack2(v0, v1), pack2(v2, v3) };
        *(uint2*)(krow + (ot-16)*16 + 4*g) = st;
      }
    } else {
      // swapped: C[j][o]: j = 4g+r (pixel), o = ot*16+lo
      #pragma unroll
      for (int kc = 0; kc < 8; ++kc) {
        bf16x8 wf = *(const bf16x8*)(Wl + lo*256 + ((kc*4 + g) ^ sw) * 8);
        acc = __builtin_amdgcn_mfma_f32_16x16x32_bf16(hf[kc], wf, acc, 0, 0, 0);
      }
      int oc = (ot - 32) * 16 + lo;
      float bv = b_qkv[512 + oc];
      uint2 st = { pack2(acc[0]+bv, acc[1]+bv), pack2(acc[2]+bv, acc[3]+bv) };
      *(uint2*)(vS + ((size_t)(b * NC + oc)) * NHW + n0 + w*16 + 4*g) = st;
    }
  }
}

// ---------------- scalar qkv fallback (small-workspace path) ----------------
__global__ __launch_bounds__(256) void qkv_scalar_k(const float* __restrict__ x,
                                             const float* __restrict__ coef,
                                             const float* __restrict__ w_qkv,
                                             const float* __restrict__ b_qkv,
                                             u16* __restrict__ qT, u16* __restrict__ kT,
                                             u16* __restrict__ vS){
  int idx0 = blockIdx.x;
  int idx = (idx0 >> 3) + (idx0 & 7) * 768;
  int og = idx % 48;
  int t  = idx / 48;
  int nc = t & 15;
  int b  = t >> 4;
  int n  = nc * 256 + threadIdx.x;
  const float* xb = x + (size_t)b * NC * NHW + n;
  const float* cf = coef + b * NC * 2;
  int ob = og * 16;
  float acc[16];
  #pragma unroll
  for (int j = 0; j < 16; ++j) acc[j] = b_qkv[ob + j];
  for (int c = 0; c < NC; ++c) {
    float h = xb[(size_t)c * NHW] * cf[2*c] + cf[2*c+1];
    const float* wr = w_qkv + (size_t)ob * NC + c;
    #pragma unroll
    for (int j = 0; j < 16; ++j) acc[j] += h * wr[(size_t)j * NC];
  }
  if (ob < 512) {
    float sc = (ob < 256) ? 0.0625f : 1.0f;
    union { u16 h[16]; uint4 q[2]; } u;
    #pragma unroll
    for (int j = 0; j < 16; ++j) u.h[j] = f2bf(acc[j] * sc);
    u16* p = (ob < 256) ? (qT + ((size_t)(b*NHW + n))*NC + ob)
                        : (kT + ((size_t)(b*NHW + n))*NC + (ob - 256));
    *(uint4*)p = u.q[0];
    *(uint4*)(p + 8) = u.q[1];
  } else {
    u16* p = vS + ((size_t)(b*NC) + (ob - 512)) * NHW + n;
    #pragma unroll
    for (int j = 0; j < 16; ++j) p[(size_t)j * NHW] = f2bf(acc[j]);
  }
}

// ---------------- MFMA flash attention + fused proj + residual ----------------
template<int WBF>
__global__ __launch_bounds__(256, 2) void attn_k(const float* __restrict__ x,
    const u16* __restrict__ qT, const u16* __restrict__ kT, const u16* __restrict__ vS,
    const float* __restrict__ w_proj, const u16* __restrict__ wbf,
    const float* __restrict__ b_proj, float* __restrict__ out){
  __shared__ char smem[73728];
  u16* Klds = (u16*)smem;               // [64][256] bf16, chunk^=(row&7) swizzle
  u16* Vlds = (u16*)(smem + 32768);     // [256][64] bf16, swizzled
  float* Olds = (float*)smem;           // epilogue alias: [4][16][256] f32

  int bid = blockIdx.x;
  int wg = ((bid & 7) << 6) | (bid >> 3);
  int b  = wg >> 6;
  int n0 = (wg & 63) << 6;
  int w = threadIdx.x >> 6, lane = threadIdx.x & 63;
  int lo = lane & 15, g = lane >> 4;
  int sw = lo & 7;

  const u16* qTb = qT + (size_t)b * NHW * NC;
  const u16* kTb = kT + (size_t)b * NHW * NC;
  const u16* vSb = vS + (size_t)b * NC * NHW;

  bf16x8 qf[8];
  {
    const u16* qp = qTb + (size_t)(n0 + w*16 + lo) * NC + g*8;
    #pragma unroll
    for (int kc = 0; kc < 8; ++kc) qf[kc] = *(const bf16x8*)(qp + kc*32);
  }

  int koff[8], voff[8];
  #pragma unroll
  for (int i = 0; i < 8; ++i) {
    int o = w*8192 + i*1024 + lane*16;
    int mr = o >> 9;
    int kch = ((o >> 4) & 31) ^ (mr & 7);
    koff[i] = mr*NC + kch*8;
    int cr = o >> 7;
    int vch = ((o >> 4) & 7) ^ (cr & 7);
    voff[i] = cr*NHW + vch*8;
  }

  f32x4 oacc[16];
  #pragma unroll
  for (int i = 0; i < 16; ++i) oacc[i] = (f32x4){0.f,0.f,0.f,0.f};
  float mrun = -1e30f, lrun = 0.f;

  char* Pw = smem + 65536 + w*2048;

  for (int m0 = 0; m0 < NHW; m0 += 64) {
    __syncthreads();
    const u16* kp = kTb + (size_t)m0 * NC;
    const u16* vp = vSb + m0;
    #pragma unroll
    for (int i = 0; i < 8; ++i) {
      GLD16(kp + koff[i], smem + w*8192 + i*1024);
      GLD16(vp + voff[i], smem + 32768 + w*8192 + i*1024);
    }
    __syncthreads();

    f32x4 st[4];
    #pragma unroll
    for (int mt = 0; mt < 4; ++mt) st[mt] = (f32x4){0.f,0.f,0.f,0.f};
    #pragma unroll
    for (int kc = 0; kc < 8; ++kc) {
      #pragma unroll
      for (int mt = 0; mt < 4; ++mt) {
        int ch = (kc*4 + g) ^ sw;
        bf16x8 kf = *(const bf16x8*)(Klds + (mt*16 + lo)*NC + ch*8);
        st[mt] = __builtin_amdgcn_mfma_f32_16x16x32_bf16(kf, qf[kc], st[mt], 0, 0, 0);
      }
    }

    float pmax = -1e30f;
    #pragma unroll
    for (int mt = 0; mt < 4; ++mt)
      #pragma unroll
      for (int r = 0; r < 4; ++r) pmax = fmaxf(pmax, st[mt][r]);
    pmax = fmaxf(pmax, __shfl_xor(pmax, 16));
    pmax = fmaxf(pmax, __shfl_xor(pmax, 32));

    if (!__all(pmax - mrun <= 8.f)) {
      float mnew = fmaxf(mrun, pmax);
      float corr = __expf(mrun - mnew);
      mrun = mnew;
      lrun *= corr;
      float c0 = __shfl(corr, 4*g+0), c1 = __shfl(corr, 4*g+1);
      float c2 = __shfl(corr, 4*g+2), c3 = __shfl(corr, 4*g+3);
      #pragma unroll
      for (int ct = 0; ct < 16; ++ct) {
        oacc[ct][0] *= c0; oacc[ct][1] *= c1; oacc[ct][2] *= c2; oacc[ct][3] *= c3;
      }
    }

    float psum = 0.f;
    #pragma unroll
    for (int mt = 0; mt < 4; ++mt) {
      float p0 = __expf(st[mt][0] - mrun);
      float p1 = __expf(st[mt][1] - mrun);
      float p2 = __expf(st[mt][2] - mrun);
      float p3 = __expf(st[mt][3] - mrun);
      psum += (p0 + p1) + (p2 + p3);
      uint2 pk = { pack2(p0, p1), pack2(p2, p3) };
      *(uint2*)(Pw + lo*128 + ((((2*mt + (g>>1)) ^ sw)) << 4) + ((g&1) << 3)) = pk;
    }
    psum += __shfl_xor(psum, 16);
    psum += __shfl_xor(psum, 32);
    lrun += psum;

    #pragma unroll
    for (int ks = 0; ks < 2; ++ks) {
      bf16x8 pa = *(const bf16x8*)(Pw + lo*128 + (((ks*4 + g) ^ sw) << 4));
      #pragma unroll
      for (int ct = 0; ct < 16; ++ct) {
        int ch = (ks*4 + g) ^ sw;
        bf16x8 vf = *(const bf16x8*)(Vlds + (ct*16 + lo)*64 + ch*8);
        oacc[ct] = __builtin_amdgcn_mfma_f32_16x16x32_bf16(pa, vf, oacc[ct], 0, 0, 0);
      }
    }
  }

  __syncthreads();
  float linv = 1.f / lrun;
  float l0 = __shfl(linv, 4*g+0), l1 = __shfl(linv, 4*g+1);
  float l2 = __shfl(linv, 4*g+2), l3 = __shfl(linv, 4*g+3);
  float* Ow = Olds + w*4096;
  #pragma unroll
  for (int ct = 0; ct < 16; ++ct) {
    int col = ct*16 + lo;
    Ow[(4*g+0)*256 + col] = oacc[ct][0] * l0;
    Ow[(4*g+1)*256 + col] = oacc[ct][1] * l1;
    Ow[(4*g+2)*256 + col] = oacc[ct][2] * l2;
    Ow[(4*g+3)*256 + col] = oacc[ct][3] * l3;
  }

  f32x4 pacc[16];
  #pragma unroll
  for (int i = 0; i < 16; ++i) pacc[i] = (f32x4){0.f,0.f,0.f,0.f};
  #pragma unroll
  for (int ks = 0; ks < 8; ++ks) {
    const float* ap = Ow + lo*256 + ks*32 + g*8;
    float4 a0 = *(const float4*)ap;
    float4 a1 = *(const float4*)(ap + 4);
    union { u16 h[8]; bf16x8 v; } au;
    au.h[0]=f2bf(a0.x); au.h[1]=f2bf(a0.y); au.h[2]=f2bf(a0.z); au.h[3]=f2bf(a0.w);
    au.h[4]=f2bf(a1.x); au.h[5]=f2bf(a1.y); au.h[6]=f2bf(a1.z); au.h[7]=f2bf(a1.w);
    bf16x8 af = au.v;
    #pragma unroll
    for (int ot = 0; ot < 16; ++ot) {
      bf16x8 bf;
      if (WBF) {
        bf = *(const bf16x8*)(wbf + (size_t)(ot*16 + lo)*NC + ks*32 + g*8);
      } else {
        const float* wp = w_proj + (size_t)(ot*16 + lo)*NC + ks*32 + g*8;
        float4 b0 = *(const float4*)wp;
        float4 b1 = *(const float4*)(wp + 4);
        union { u16 h[8]; bf16x8 v; } bu;
        bu.h[0]=f2bf(b0.x); bu.h[1]=f2bf(b0.y); bu.h[2]=f2bf(b0.z); bu.h[3]=f2bf(b0.w);
        bu.h[4]=f2bf(b1.x); bu.h[5]=f2bf(b1.y); bu.h[6]=f2bf(b1.z); bu.h[7]=f2bf(b1.w);
        bf = bu.v;
      }
      pacc[ot] = __builtin_amdgcn_mfma_f32_16x16x32_bf16(af, bf, pacc[ot], 0, 0, 0);
    }
  }

  int nrow = n0 + w*16 + 4*g;
  #pragma unroll
  for (int ot = 0; ot < 16; ++ot) {
    int o = ot*16 + lo;
    float bp = b_proj[o];
    size_t base = ((size_t)(b*NC + o)) * NHW + nrow;
    float4 xr = *(const float4*)(x + base);
    float4 ov = { pacc[ot][0] + bp + xr.x, pacc[ot][1] + bp + xr.y,
                  pacc[ot][2] + bp + xr.z, pacc[ot][3] + bp + xr.w };
    *(float4*)(out + base) = ov;
  }
}

extern "C" void kernel_launch(void* const* d_in, const int* in_sizes, int n_in,
                              void* d_out, int out_size, void* d_ws, size_t ws_size,
                              hipStream_t stream) {
  const float* x      = (const float*)d_in[0];
  const float* gamma  = (const float*)d_in[1];
  const float* beta   = (const float*)d_in[2];
  const float* w_qkv  = (const float*)d_in[3];
  const float* b_qkv  = (const float*)d_in[4];
  const float* w_proj = (const float*)d_in[5];
  const float* b_proj = (const float*)d_in[6];
  float* out = (float*)d_out;

  float* stats = (float*)d_ws;                        // 512 f
  float* coef  = stats + 2 * NB * NG;                 // 4096 f
  u16* qT = (u16*)((char*)d_ws + 18432);              // [b][n][c] 16MB
  u16* kT = qT + (size_t)NB * NHW * NC;               // [b][n][c] 16MB
  u16* vS = kT + (size_t)NB * NHW * NC;               // [b][c][n] 16MB
  u16* wbf  = vS + (size_t)NB * NC * NHW;             // proj W bf16, 128KB
  u16* wqbf = wbf + NC * NC;                          // qkv W bf16, 384KB
  size_t need = 18432 + (size_t)3 * NB * NHW * NC * 2
              + (size_t)NC * NC * 2 + (size_t)3 * NC * NC * 2;

  gn_stats_k<<<NB * NG, 256, 0, stream>>>(x, stats);
  gn_coef_k<<<(NB * NC + 255) / 256, 256, 0, stream>>>(stats, gamma, beta, coef);
  if (ws_size >= need) {
    cvtw_k<<<NC * NC / 256, 256, 0, stream>>>(w_proj, wbf);
    cvtw_k<<<3 * NC * NC / 256, 256, 0, stream>>>(w_qkv, wqbf);
    qkv_mfma_k<<<512, 256, 0, stream>>>(x, coef, wqbf, b_qkv, qT, kT, vS);
    attn_k<1><<<512, 256, 0, stream>>>(x, qT, kT, vS, w_proj, wbf, b_proj, out);
  } else {
    qkv_scalar_k<<<NB * 16 * 48, 256, 0, stream>>>(x, coef, w_qkv, b_qkv, qT, kT, vS);
    attn_k<0><<<512, 256, 0, stream>>>(x, qT, kT, vS, w_proj, wbf, b_proj, out);
  }
}